// Round 1
// baseline (209.387 us; speedup 1.0000x reference)
//
#include <hip/hip_runtime.h>
#include <hip/hip_bf16.h>

// GAT layer: out = h = x @ W^T  (N=200000 x 128, fp32 in / fp32 out), then
// E=500 edges: out[dst] += 0.1 * leaky_relu(attn, 0.2) * h[src].
//
// K1: fp32 -> bf16 MFMA GEMM, LDS-FREE design:
//   - W (128x128) lives in 128 VGPRs per wave as 32 bf16x8 A-fragments,
//     loaded once per wave (L2-hot, amortized over ~6 grid-stride tiles).
//   - MFMA operands SWAPPED vs naive (A=W, B=x): D row = out col, D col =
//     x row  ==> acc regs are 4 consecutive out columns ==> float4 stores.
//     x B-fragment layout (col=lane&15 -> x row) keeps the load pattern and
//     accumulation order identical to the verified previous version.
//   - Persistent waves: 512 blocks x 4 waves = 2048 waves (8/CU at
//     __launch_bounds__(256,2), ~225 VGPR), grid-stride over 16-row tiles
//     with 1-deep x prefetch: loads stay in flight across cvt+MFMA+store.
//   - No LDS, no __syncthreads, no lgkmcnt chains, no bank conflicts.
// K2 (phase A): per-edge attn from h (read from `out`), contribution vectors
//     into d_ws. All h reads complete before any update -> race-free.
// K3 (phase B): fp32 atomicAdd scatter of contributions into out[dst].

typedef __attribute__((ext_vector_type(8))) short bf16x8;   // 8 bf16 = 4 VGPRs
typedef __attribute__((ext_vector_type(4))) float f32x4;

__device__ __forceinline__ bf16x8 pack_bf16x8(float4 v0, float4 v1) {
  union { bf16x8 v; __hip_bfloat16 h[8]; } u;
  u.h[0] = __float2bfloat16(v0.x); u.h[1] = __float2bfloat16(v0.y);
  u.h[2] = __float2bfloat16(v0.z); u.h[3] = __float2bfloat16(v0.w);
  u.h[4] = __float2bfloat16(v1.x); u.h[5] = __float2bfloat16(v1.y);
  u.h[6] = __float2bfloat16(v1.z); u.h[7] = __float2bfloat16(v1.w);
  return u.v;
}

__global__ __launch_bounds__(256, 2) void gat_gemm_kernel(
    const float* __restrict__ x,
    const float* __restrict__ W,
    float* __restrict__ out,
    int N) {
  const int wave = threadIdx.x >> 6;
  const int lane = threadIdx.x & 63;
  const int m = lane & 15;     // A row (W row = out col) / B col (x row)
  const int q = lane >> 4;     // quad 0..3 -> k-subchunk q*8, D reg row q*4+j

  // --- W fragments, register-resident for the whole kernel (128 VGPRs). ---
  // wf[nt*4+s]: lane holds W[nt*16+m][s*32 + q*8 .. +7] as bf16.
  bf16x8 wf[32];
  #pragma unroll
  for (int nt = 0; nt < 8; ++nt) {
    #pragma unroll
    for (int s = 0; s < 4; ++s) {
      const float* wp = W + (nt * 16 + m) * 128 + s * 32 + q * 8;
      float4 v0 = *reinterpret_cast<const float4*>(wp);
      float4 v1 = *reinterpret_cast<const float4*>(wp + 4);
      wf[nt * 4 + s] = pack_bf16x8(v0, v1);
    }
  }

  const int tiles = N >> 4;              // 16-row tiles (N % 16 == 0)
  const int tstep = (int)gridDim.x * 4;  // one tile per wave per round
  int t = (int)blockIdx.x * 4 + wave;
  if (t >= tiles) return;                // wave-uniform; no barriers anywhere

  // Prefetch x for the first tile: lane reads x[t*16+m][s*32+q*8 .. +7].
  float4 raw[8];
  {
    const float* xr = x + (t * 16 + m) * 128;
    #pragma unroll
    for (int s = 0; s < 4; ++s) {
      raw[2 * s]     = *reinterpret_cast<const float4*>(xr + s * 32 + q * 8);
      raw[2 * s + 1] = *reinterpret_cast<const float4*>(xr + s * 32 + q * 8 + 4);
    }
  }

  while (true) {
    // Convert current tile's x to bf16 B-fragments (frees raw for reuse).
    bf16x8 afrag[4];
    #pragma unroll
    for (int s = 0; s < 4; ++s) afrag[s] = pack_bf16x8(raw[2 * s], raw[2 * s + 1]);

    // Issue next tile's loads NOW -> in flight across MFMA + store + wrap.
    const int tn = t + tstep;
    if (tn < tiles) {
      const float* xr = x + (tn * 16 + m) * 128;
      #pragma unroll
      for (int s = 0; s < 4; ++s) {
        raw[2 * s]     = *reinterpret_cast<const float4*>(xr + s * 32 + q * 8);
        raw[2 * s + 1] = *reinterpret_cast<const float4*>(xr + s * 32 + q * 8 + 4);
      }
    }

    // D[r][c] = sum_k W[ntbase+r][k] * x[t*16+c][k]; all operands in regs.
    f32x4 acc[8];
    #pragma unroll
    for (int nt = 0; nt < 8; ++nt) acc[nt] = (f32x4){0.f, 0.f, 0.f, 0.f};
    #pragma unroll
    for (int s = 0; s < 4; ++s) {
      #pragma unroll
      for (int nt = 0; nt < 8; ++nt)
        acc[nt] = __builtin_amdgcn_mfma_f32_16x16x32_bf16(wf[nt * 4 + s],
                                                          afrag[s], acc[nt],
                                                          0, 0, 0);
    }

    // D (reg j, lane) -> out[t*16 + m][nt*16 + q*4 + j]: float4 per nt.
    float* orow = out + (t * 16 + m) * 128 + q * 4;
    #pragma unroll
    for (int nt = 0; nt < 8; ++nt)
      *reinterpret_cast<f32x4*>(orow + nt * 16) = acc[nt];

    if (tn >= tiles) break;
    t = tn;
  }
}

__device__ __forceinline__ int detect_i64(const int* eidx) {
  int or_odd = 0;
  #pragma unroll
  for (int k = 0; k < 16; ++k) or_odd |= eidx[2 * k + 1];
  return or_odd == 0;   // int64 little-endian: high words all zero
}

// Phase A: one block per edge. Read h rows from `out` (pure read), compute
// attn, write contribution vector 0.1*attn*h_src to ws. No races.
__global__ __launch_bounds__(128) void gat_edge_attn(
    const int* __restrict__ eidx,
    const float* __restrict__ a,       // [4, 64]
    const float* __restrict__ h,       // == out, post-GEMM
    float* __restrict__ contrib,       // [E, 128] in ws
    int E) {
  const int e = blockIdx.x;
  const int c = threadIdx.x;
  const bool is64 = detect_i64(eidx);
  const int src = is64 ? eidx[2 * e] : eidx[e];
  const int dst = is64 ? eidx[2 * (E + e)] : eidx[E + e];

  const float hs = h[(long)src * 128 + c];
  const float hd = h[(long)dst * 128 + c];

  const int head = c >> 5, d = c & 31;
  float term = a[head * 64 + d] * hs + a[head * 64 + 32 + d] * hd;
  // reduce over the 32 lanes of this head (heads occupy 32-lane halves)
  term += __shfl_xor(term, 16);
  term += __shfl_xor(term, 8);
  term += __shfl_xor(term, 4);
  term += __shfl_xor(term, 2);
  term += __shfl_xor(term, 1);
  const float attn = term >= 0.f ? term : 0.2f * term;   // leaky_relu(0.2)

  contrib[(long)e * 128 + c] = 0.1f * attn * hs;
}

// Phase B: atomic scatter-add of contributions (duplicate dst handled by HW).
__global__ __launch_bounds__(128) void gat_edge_scatter(
    const int* __restrict__ eidx,
    const float* __restrict__ contrib,
    float* __restrict__ out,
    int E) {
  const int e = blockIdx.x;
  const int c = threadIdx.x;
  const bool is64 = detect_i64(eidx);
  const int dst = is64 ? eidx[2 * (E + e)] : eidx[E + e];
  atomicAdd(&out[(long)dst * 128 + c], contrib[(long)e * 128 + c]);
}

extern "C" void kernel_launch(void* const* d_in, const int* in_sizes, int n_in,
                              void* d_out, int out_size, void* d_ws, size_t ws_size,
                              hipStream_t stream) {
  const float* x  = (const float*)d_in[0];
  const int* eidx = (const int*)d_in[1];
  const float* W  = (const float*)d_in[2];
  const float* a  = (const float*)d_in[3];
  float* out = (float*)d_out;
  float* contrib = (float*)d_ws;     // needs E*128*4 = 256 KB

  const int N = in_sizes[0] / 128;   // 200000
  const int E = in_sizes[1] / 2;     // 500

  const int tiles = N / 16;          // 12500
  int blocks = (tiles + 3) / 4;
  if (blocks > 512) blocks = 512;    // 512 blocks x 4 waves = 2048 persistent waves
  gat_gemm_kernel<<<blocks, 256, 0, stream>>>(x, W, out, N);
  gat_edge_attn<<<E, 128, 0, stream>>>(eidx, a, out, contrib, E);
  gat_edge_scatter<<<E, 128, 0, stream>>>(eidx, contrib, out, E);
}

// Round 2
// 202.176 us; speedup vs baseline: 1.0357x; 1.0357x over previous
//
#include <hip/hip_runtime.h>
#include <hip/hip_bf16.h>

// GAT layer: out = h = x @ W^T  (N=200000 x 128, fp32 in / fp32 out), then
// E=500 edges: out[dst] += 0.1 * leaky_relu(attn, 0.2) * h[src].
//
// K1: fp32 -> bf16 MFMA GEMM, LDS-FREE, register-resident W:
//   - W (128x128) lives in 128 VGPRs per wave as 32 bf16x8 A-fragments.
//     Round-1 post-mortem: the compiler SANK these loads into the loop
//     (VGPR_Count=128 is impossible with wf live), re-loading W from L2
//     every iteration -> latency chains. Fix: pin each fragment with an
//     empty inline-asm "+v" constraint, making it opaque/unrematerializable.
//   - MFMA operands swapped (A=W, B=x): acc regs are 4 consecutive out
//     columns -> float4 stores. Verified numerically in rounds 0-1.
//   - Persistent waves: 512 blocks x 4 waves = 2048 waves (2/SIMD at
//     ~224 VGPR), grid-stride over 16-row tiles, 1-deep x prefetch.
//     Steady state: wait(8KB x) -> cvt -> issue next 8KB -> 32 reg-MFMA ->
//     8x float4 store. Each wave keeps 8KB outstanding ~95% of the time:
//     64KB/CU in flight >> ~13KB Little's-law requirement for 6.3 TB/s.
//   - No LDS, no barriers, no lgkmcnt chains, no bank conflicts.
// K2 (phase A): per-edge attn from h (read from `out`), contribution vectors
//     into d_ws. All h reads complete before any update -> race-free.
// K3 (phase B): fp32 atomicAdd scatter of contributions into out[dst].

typedef __attribute__((ext_vector_type(8))) short bf16x8;   // 8 bf16 = 4 VGPRs
typedef __attribute__((ext_vector_type(4))) float f32x4;

__device__ __forceinline__ bf16x8 pack_bf16x8(float4 v0, float4 v1) {
  union { bf16x8 v; __hip_bfloat16 h[8]; } u;
  u.h[0] = __float2bfloat16(v0.x); u.h[1] = __float2bfloat16(v0.y);
  u.h[2] = __float2bfloat16(v0.z); u.h[3] = __float2bfloat16(v0.w);
  u.h[4] = __float2bfloat16(v1.x); u.h[5] = __float2bfloat16(v1.y);
  u.h[6] = __float2bfloat16(v1.z); u.h[7] = __float2bfloat16(v1.w);
  return u.v;
}

__global__ __launch_bounds__(256, 2) void gat_gemm_kernel(
    const float* __restrict__ x,
    const float* __restrict__ W,
    float* __restrict__ out,
    int N) {
  const int wave = threadIdx.x >> 6;
  const int lane = threadIdx.x & 63;
  const int m = lane & 15;     // A row (W row = out col) / B col (x row)
  const int q = lane >> 4;     // quad 0..3 -> k-subchunk q*8, D reg row q*4+j

  // --- W fragments, register-resident for the whole kernel (128 VGPRs). ---
  // wf[nt*4+s]: lane holds W[nt*16+m][s*32 + q*8 .. +7] as bf16.
  bf16x8 wf[32];
  #pragma unroll
  for (int nt = 0; nt < 8; ++nt) {
    #pragma unroll
    for (int s = 0; s < 4; ++s) {
      const float* wp = W + (nt * 16 + m) * 128 + s * 32 + q * 8;
      float4 v0 = *reinterpret_cast<const float4*>(wp);
      float4 v1 = *reinterpret_cast<const float4*>(wp + 4);
      wf[nt * 4 + s] = pack_bf16x8(v0, v1);
    }
  }
  // PIN: make each fragment opaque so the compiler cannot sink/remat the
  // W loads into the loop (round-1 failure mode). Forces ~128 live VGPRs.
  #pragma unroll
  for (int i = 0; i < 32; ++i) asm volatile("" : "+v"(wf[i]));

  const int tiles = N >> 4;              // 16-row tiles (N % 16 == 0)
  const int tstep = (int)gridDim.x * 4;  // one tile per wave per round
  int t = (int)blockIdx.x * 4 + wave;
  if (t >= tiles) return;                // wave-uniform; no barriers anywhere

  // Prefetch x for the first tile: lane reads x[t*16+m][s*32+q*8 .. +7].
  float4 raw[8];
  {
    const float* xr = x + (t * 16 + m) * 128;
    #pragma unroll
    for (int s = 0; s < 4; ++s) {
      raw[2 * s]     = *reinterpret_cast<const float4*>(xr + s * 32 + q * 8);
      raw[2 * s + 1] = *reinterpret_cast<const float4*>(xr + s * 32 + q * 8 + 4);
    }
  }

  while (true) {
    // Convert current tile's x to bf16 B-fragments (frees raw for reuse).
    bf16x8 afrag[4];
    #pragma unroll
    for (int s = 0; s < 4; ++s) afrag[s] = pack_bf16x8(raw[2 * s], raw[2 * s + 1]);

    // Issue next tile's loads NOW -> in flight across MFMA + store + wrap.
    const int tn = t + tstep;
    if (tn < tiles) {
      const float* xr = x + (tn * 16 + m) * 128;
      #pragma unroll
      for (int s = 0; s < 4; ++s) {
        raw[2 * s]     = *reinterpret_cast<const float4*>(xr + s * 32 + q * 8);
        raw[2 * s + 1] = *reinterpret_cast<const float4*>(xr + s * 32 + q * 8 + 4);
      }
    }

    // D[r][c] = sum_k W[ntbase+r][k] * x[t*16+c][k]; all operands in regs.
    f32x4 acc[8];
    #pragma unroll
    for (int nt = 0; nt < 8; ++nt) acc[nt] = (f32x4){0.f, 0.f, 0.f, 0.f};
    #pragma unroll
    for (int s = 0; s < 4; ++s) {
      #pragma unroll
      for (int nt = 0; nt < 8; ++nt)
        acc[nt] = __builtin_amdgcn_mfma_f32_16x16x32_bf16(wf[nt * 4 + s],
                                                          afrag[s], acc[nt],
                                                          0, 0, 0);
    }

    // D (reg j, lane) -> out[t*16 + m][nt*16 + q*4 + j]: float4 per nt.
    float* orow = out + (t * 16 + m) * 128 + q * 4;
    #pragma unroll
    for (int nt = 0; nt < 8; ++nt)
      *reinterpret_cast<f32x4*>(orow + nt * 16) = acc[nt];

    if (tn >= tiles) break;
    t = tn;
  }
}

__device__ __forceinline__ int detect_i64(const int* eidx) {
  int or_odd = 0;
  #pragma unroll
  for (int k = 0; k < 16; ++k) or_odd |= eidx[2 * k + 1];
  return or_odd == 0;   // int64 little-endian: high words all zero
}

// Phase A: one block per edge. Read h rows from `out` (pure read), compute
// attn, write contribution vector 0.1*attn*h_src to ws. No races.
__global__ __launch_bounds__(128) void gat_edge_attn(
    const int* __restrict__ eidx,
    const float* __restrict__ a,       // [4, 64]
    const float* __restrict__ h,       // == out, post-GEMM
    float* __restrict__ contrib,       // [E, 128] in ws
    int E) {
  const int e = blockIdx.x;
  const int c = threadIdx.x;
  const bool is64 = detect_i64(eidx);
  const int src = is64 ? eidx[2 * e] : eidx[e];
  const int dst = is64 ? eidx[2 * (E + e)] : eidx[E + e];

  const float hs = h[(long)src * 128 + c];
  const float hd = h[(long)dst * 128 + c];

  const int head = c >> 5, d = c & 31;
  float term = a[head * 64 + d] * hs + a[head * 64 + 32 + d] * hd;
  // reduce over the 32 lanes of this head (heads occupy 32-lane halves)
  term += __shfl_xor(term, 16);
  term += __shfl_xor(term, 8);
  term += __shfl_xor(term, 4);
  term += __shfl_xor(term, 2);
  term += __shfl_xor(term, 1);
  const float attn = term >= 0.f ? term : 0.2f * term;   // leaky_relu(0.2)

  contrib[(long)e * 128 + c] = 0.1f * attn * hs;
}

// Phase B: atomic scatter-add of contributions (duplicate dst handled by HW).
__global__ __launch_bounds__(128) void gat_edge_scatter(
    const int* __restrict__ eidx,
    const float* __restrict__ contrib,
    float* __restrict__ out,
    int E) {
  const int e = blockIdx.x;
  const int c = threadIdx.x;
  const bool is64 = detect_i64(eidx);
  const int dst = is64 ? eidx[2 * (E + e)] : eidx[E + e];
  atomicAdd(&out[(long)dst * 128 + c], contrib[(long)e * 128 + c]);
}

extern "C" void kernel_launch(void* const* d_in, const int* in_sizes, int n_in,
                              void* d_out, int out_size, void* d_ws, size_t ws_size,
                              hipStream_t stream) {
  const float* x  = (const float*)d_in[0];
  const int* eidx = (const int*)d_in[1];
  const float* W  = (const float*)d_in[2];
  const float* a  = (const float*)d_in[3];
  float* out = (float*)d_out;
  float* contrib = (float*)d_ws;     // needs E*128*4 = 256 KB

  const int N = in_sizes[0] / 128;   // 200000
  const int E = in_sizes[1] / 2;     // 500

  const int tiles = N / 16;          // 12500
  int blocks = (tiles + 3) / 4;
  if (blocks > 512) blocks = 512;    // 512 blocks x 4 waves = 2048 persistent waves
  gat_gemm_kernel<<<blocks, 256, 0, stream>>>(x, W, out, N);
  gat_edge_attn<<<E, 128, 0, stream>>>(eidx, a, out, contrib, E);
  gat_edge_scatter<<<E, 128, 0, stream>>>(eidx, contrib, out, E);
}